// Round 3
// baseline (698.639 us; speedup 1.0000x reference)
//
#include <hip/hip_runtime.h>
#include <hip/hip_bf16.h>
#include <math.h>

// ---------------- workspace layout (bytes, 256-aligned) ----------------
#define WS_T     0           // t1,t2,t3: 3 * 64*256 f32 = 196608 B
#define WS_F     196608      // F tables: 4*8*512 f32 = 65536 B
#define WS_W2    262144      // W2[o][h]: 256*8 f32 = 8192 B
#define WS_C     270336      // c[o]: 256 f32
#define WS_RS1   271360      // rs1[oc]: 512 f32
#define WS_ST1   273408      // stats1: 1024 f32 (sum, sumsq)
#define WS_ST2   277504      // stats2: 2048 f32
#define WS_WD1B  285696      // wd1 bf16: 512*1536*2 = 1572864 B
#define WS_WD2B  1858560     // wd2 bf16: 1024*512*2 = 1048576 B
#define WS_S3    2907136     // S3 bf16 [n=512][k=1536] = 1572864 B
#define WS_ABT   4480000     // AbfT bf16 [64][256][512] = 16777216 B
#define WS_TT    21257216    // T f32 [512][512] = 1048576 B
#define WS_END   22305792

typedef __attribute__((ext_vector_type(4))) float f32x4;
typedef __attribute__((ext_vector_type(2))) float f32x2;
typedef __attribute__((ext_vector_type(8))) short bf16x8;
typedef __attribute__((ext_vector_type(4))) unsigned int u32x4;

__device__ __forceinline__ unsigned short f2bf(float f) {
    union { __hip_bfloat16 h; unsigned short u; } cv;
    cv.h = __float2bfloat16(f);
    return cv.u;
}

// ---------------- K0: precompute (F Toeplitz tables, W2, c, rs1, bf16 weights, zero T)
__global__ __launch_bounds__(256) void k_prep(
    const float* __restrict__ wq, const float* __restrict__ bq,
    const float* __restrict__ wk, const float* __restrict__ bk,
    const float* __restrict__ wv, const float* __restrict__ bv,
    const float* __restrict__ wfc, const float* __restrict__ bfc,
    const float* __restrict__ wd1, const float* __restrict__ wd2,
    char* __restrict__ ws)
{
    __shared__ float sred[4];
    int bid = blockIdx.x, tid = threadIdx.x;
    if (bid < 768) {                      // wd1 -> bf16 (512x1536)
        unsigned short* out = (unsigned short*)(ws + WS_WD1B);
        int idx = (bid*256 + tid)*4;
        f32x4 v = *(const f32x4*)(wd1 + idx);
        out[idx]   = f2bf(v[0]); out[idx+1] = f2bf(v[1]);
        out[idx+2] = f2bf(v[2]); out[idx+3] = f2bf(v[3]);
    } else if (bid < 1280) {              // wd2 -> bf16 (1024x512)
        unsigned short* out = (unsigned short*)(ws + WS_WD2B);
        int idx = ((bid-768)*256 + tid)*4;
        f32x4 v = *(const f32x4*)(wd2 + idx);
        out[idx]   = f2bf(v[0]); out[idx+1] = f2bf(v[1]);
        out[idx+2] = f2bf(v[2]); out[idx+3] = f2bf(v[3]);
    } else if (bid < 1792) {              // rs1[oc] = sum_k wd1[oc][k]
        int oc = bid - 1280;
        float acc = 0.f;
        for (int k = tid; k < 1536; k += 256) acc += wd1[oc*1536 + k];
        for (int off = 32; off; off >>= 1) acc += __shfl_down(acc, off);
        int lane = tid & 63, w = tid >> 6;
        if (lane == 0) sred[w] = acc;
        __syncthreads();
        if (tid == 0) ((float*)(ws+WS_RS1))[oc] = sred[0]+sred[1]+sred[2]+sred[3];
    } else if (bid < 1856) {              // F[tab][h][d], d = (k-q)+255 in [0,511)
        int e = (bid-1792)*256 + tid;
        if (e < 16352) {
            int tab = e / 4088; int rem = e - tab*4088;
            int h = rem / 511;  int d = rem - h*511;
            const float* u = (tab < 2) ? wq : bq;
            const float* v = (tab & 1) ? bk : wk;
            float delta = (float)(d - 255);
            float acc = 0.f;
            for (int j = 0; j < 16; ++j) {
                int m = 16*h + j;
                float th = exp2f((float)m * -0.10381025296082607f); // 10000^(-m/128)
                float sn, cs; sincosf(delta * th, &sn, &cs);
                float u0 = u[2*m], u1 = u[2*m+1], v0 = v[2*m], v1 = v[2*m+1];
                acc += cs*(u0*v0 + u1*v1) + sn*(u1*v0 - u0*v1);
            }
            ((float*)(ws+WS_F))[tab*4096 + h*512 + d] = acc * 0.0625f; // fold 1/sqrt(256)
        }
    } else if (bid < 1864) {              // W2[o][h] = sum_{d in head h} wv[d]*wfc[o][d]
        int e = (bid-1856)*256 + tid;     // 2048 entries
        int o = e >> 3, h = e & 7;
        float acc = 0.f;
        for (int d2 = 0; d2 < 32; ++d2) acc += wv[h*32+d2] * wfc[o*256 + h*32 + d2];
        ((float*)(ws+WS_W2))[e] = acc;
    } else if (bid == 1864) {             // c[o] = bfc[o] + sum_i wfc[o][i]*bv[i]
        int o = tid;
        float acc = bfc[o];
        for (int i2 = 0; i2 < 256; ++i2) acc += wfc[o*256+i2]*bv[i2];
        ((float*)(ws+WS_C))[o] = acc;
    } else {                              // zero T accumulators (49152 f32)
        int idx = (bid-1865)*256 + tid;
        if (idx < 49152) ((float*)(ws+WS_T))[idx] = 0.f;
    }
}

// ---------------- K1: fused resize + 1x1 conv -> t1,t2,t3 (HBM-bound)
__global__ __launch_bounds__(256) void k_tvec(
    const float* __restrict__ x1, const float* __restrict__ x2, const float* __restrict__ x3,
    const float* __restrict__ wc1, const float* __restrict__ bc1,
    const float* __restrict__ wc2, const float* __restrict__ bc2,
    const float* __restrict__ wc3, const float* __restrict__ bc3,
    char* __restrict__ ws)
{
    float* T = (float*)(ws + WS_T);
    int bid = blockIdx.x, tid = threadIdx.x;
    int p = tid, i = p >> 4, j = p & 15;
    if (bid < 512) {           // t1: 64->16 resize = avg of rows 4i+1,4i+2 cols 4j+1,4j+2
        int b = bid >> 3, cg = bid & 7;
        const float* base = x1 + (((size_t)(b*256 + cg*32)*64 + (4*i+1))*64 + (4*j+1));
        float acc = 0.f;
        for (int c = 0; c < 32; ++c) {
            const float* xp = base + (size_t)c*4096;
            acc = fmaf(wc1[cg*32+c], xp[0]+xp[1]+xp[64]+xp[65], acc);
        }
        acc *= 0.25f;
        if (cg == 0) acc += bc1[0];
        atomicAdd(&T[b*256 + p], acc);
    } else if (bid < 1024) {   // t2: 2x2 avg pool
        int lb = bid - 512; int b = lb >> 3, cg = lb & 7;
        const float* base = x2 + (((size_t)(b*512 + cg*64)*32 + 2*i)*32 + 2*j);
        float acc = 0.f;
        for (int c = 0; c < 64; ++c) {
            const float* xp = base + (size_t)c*1024;
            f32x2 r0 = *(const f32x2*)xp;
            f32x2 r1 = *(const f32x2*)(xp + 32);
            acc = fmaf(wc2[cg*64+c], r0[0]+r0[1]+r1[0]+r1[1], acc);
        }
        acc *= 0.25f;
        if (cg == 0) acc += bc2[0];
        atomicAdd(&T[16384 + b*256 + p], acc);
    } else {                   // t3: direct channel reduce
        int lb = bid - 1024; int b = lb >> 3, cg = lb & 7;
        const float* base = x3 + ((size_t)(b*1024 + cg*128)*256 + p);
        float acc = 0.f;
        for (int c = 0; c < 128; ++c)
            acc = fmaf(wc3[cg*128+c], base[(size_t)c*256], acc);
        if (cg == 0) acc += bc3[0];
        atomicAdd(&T[32768 + b*256 + p], acc);
    }
}

// ---------------- K2: all 6 attentions via Toeplitz score tables; emits s -> S3 bf16
__global__ __launch_bounds__(256) void k_attn(char* __restrict__ ws)
{
    __shared__ float teL[256], embL[256];
    __shared__ float FL[4][4][512];
    const float* T = (const float*)(ws + WS_T);
    const float* F = (const float*)(ws + WS_F);
    unsigned short* S3 = (unsigned short*)(ws + WS_S3);
    const int te_idx[6] = {0,0,0,1,1,2};
    const int em_idx[6] = {0,1,2,1,2,2};
    int bid = blockIdx.x, tid = threadIdx.x;
    int a = bid >> 7; int rem = bid & 127; int b = rem >> 1; int h0 = (rem & 1)*4;
    teL[tid]  = T[te_idx[a]*16384 + b*256 + tid];
    embL[tid] = T[em_idx[a]*16384 + b*256 + tid];
    for (int i = 0; i < 32; ++i) {
        int idx = i*256 + tid;
        int tab = idx >> 11, lh = (idx >> 9) & 3, d = idx & 511;
        FL[tab][lh][d] = F[tab*4096 + (h0+lh)*512 + d];
    }
    __syncthreads();
    int hh = tid >> 6, qb = tid & 63;
    for (int it = 0; it < 4; ++it) {
        int q = qb + it*64;
        float tq = teL[q];
        float sum = 0.f, ssum = 0.f;
        #pragma unroll 4
        for (int k = 0; k < 256; ++k) {
            int dk = k - q + 255;
            float em = embL[k];
            float sc = fmaf(tq, fmaf(em, FL[0][hh][dk], FL[1][hh][dk]),
                                fmaf(em, FL[2][hh][dk], FL[3][hh][dk]));
            float e = __expf(sc);
            sum += e;
            ssum = fmaf(e, em, ssum);
        }
        float s = ssum / sum;
        S3[(size_t)(b*8 + h0 + hh)*1536 + a*256 + q] = f2bf(s);
    }
}

// ---------------- bf16 NT GEMM: C[m][n] = sum_k A[m][k]*B[n][k] (+bias[m])
// BM=BN=128, BK=64, 4 waves, each wave 64x64 (4x4 frags of 16x16x32 MFMA)
__global__ __launch_bounds__(256) void k_gemm_nt(
    const unsigned short* __restrict__ A, const unsigned short* __restrict__ B,
    float* __restrict__ C, const float* __restrict__ bias,
    int lda, int ldb, int ldc, int K, long strideB, long strideC)
{
    __shared__ unsigned short As[128][72];   // 72 = 9*8 shorts: 16B-aligned rows, 2-way-max conflicts
    __shared__ unsigned short Bs[128][72];
    int tid = threadIdx.x;
    const unsigned short* Bp = B + (size_t)blockIdx.z * strideB;
    float* Cp = C + (size_t)blockIdx.z * strideC;
    int m0 = blockIdx.x * 128, n0 = blockIdx.y * 128;
    int lane = tid & 63, w = tid >> 6;
    int wm = (w >> 1)*64, wn = (w & 1)*64;
    int fr = lane & 15, kg = (lane >> 4)*8;
    f32x4 acc[4][4];
    #pragma unroll
    for (int mi = 0; mi < 4; ++mi)
        #pragma unroll
        for (int ni = 0; ni < 4; ++ni)
            #pragma unroll
            for (int r = 0; r < 4; ++r) acc[mi][ni][r] = 0.f;

    for (int k0 = 0; k0 < K; k0 += 64) {
        #pragma unroll
        for (int i = 0; i < 4; ++i) {
            int idx = i*256 + tid;
            int row = idx >> 3, ch = (idx & 7)*8;
            *(bf16x8*)&As[row][ch] = *(const bf16x8*)(A  + (size_t)(m0+row)*lda + k0 + ch);
            *(bf16x8*)&Bs[row][ch] = *(const bf16x8*)(Bp + (size_t)(n0+row)*ldb + k0 + ch);
        }
        __syncthreads();
        #pragma unroll
        for (int kk = 0; kk < 64; kk += 32) {
            bf16x8 af[4], bfr[4];
            #pragma unroll
            for (int mi = 0; mi < 4; ++mi) af[mi]  = *(const bf16x8*)&As[wm + mi*16 + fr][kk + kg];
            #pragma unroll
            for (int ni = 0; ni < 4; ++ni) bfr[ni] = *(const bf16x8*)&Bs[wn + ni*16 + fr][kk + kg];
            #pragma unroll
            for (int mi = 0; mi < 4; ++mi)
                #pragma unroll
                for (int ni = 0; ni < 4; ++ni)
                    acc[mi][ni] = __builtin_amdgcn_mfma_f32_16x16x32_bf16(af[mi], bfr[ni], acc[mi][ni], 0, 0, 0);
        }
        __syncthreads();
    }
    int rg = lane >> 4;
    #pragma unroll
    for (int mi = 0; mi < 4; ++mi) {
        #pragma unroll
        for (int ni = 0; ni < 4; ++ni) {
            int col = n0 + wn + ni*16 + fr;
            #pragma unroll
            for (int rr = 0; rr < 4; ++rr) {
                int rowm = m0 + wm + mi*16 + rg*4 + rr;
                float v = acc[mi][ni][rr];
                if (bias) v += bias[rowm];
                Cp[(size_t)rowm*ldc + col] = v;
            }
        }
    }
}

// ---------------- K4: BN1 stats (one block per oc; h1 recomputed, never stored)
__global__ __launch_bounds__(256) void k_stats1(char* __restrict__ ws, const float* __restrict__ bd1)
{
    const float* TT   = (const float*)(ws + WS_TT);
    const float* W2   = (const float*)(ws + WS_W2);
    const float* cvec = (const float*)(ws + WS_C);
    const float* rs1  = (const float*)(ws + WS_RS1);
    float* st1 = (float*)(ws + WS_ST1);
    __shared__ float Trow[512];
    __shared__ float reds[4], redq[4];
    int oc = blockIdx.x, tid = threadIdx.x;
    Trow[tid]       = TT[(size_t)oc*512 + tid];
    Trow[256 + tid] = TT[(size_t)oc*512 + 256 + tid];
    __syncthreads();
    f32x4 wa = *(const f32x4*)(W2 + tid*8);
    f32x4 wb = *(const f32x4*)(W2 + tid*8 + 4);
    float base = fmaf(cvec[tid], rs1[oc], bd1[oc]);
    float s = 0.f, q2 = 0.f;
    for (int b = 0; b < 64; ++b) {
        const float* tr = &Trow[b*8];
        float hv = base;
        hv = fmaf(wa[0], tr[0], hv); hv = fmaf(wa[1], tr[1], hv);
        hv = fmaf(wa[2], tr[2], hv); hv = fmaf(wa[3], tr[3], hv);
        hv = fmaf(wb[0], tr[4], hv); hv = fmaf(wb[1], tr[5], hv);
        hv = fmaf(wb[2], tr[6], hv); hv = fmaf(wb[3], tr[7], hv);
        s += hv; q2 = fmaf(hv, hv, q2);
    }
    for (int off = 32; off; off >>= 1) { s += __shfl_down(s, off); q2 += __shfl_down(q2, off); }
    int lane = tid & 63, w = tid >> 6;
    if (lane == 0) { reds[w] = s; redq[w] = q2; }
    __syncthreads();
    if (tid == 0) {
        st1[oc]     = reds[0]+reds[1]+reds[2]+reds[3];
        st1[512+oc] = redq[0]+redq[1]+redq[2]+redq[3];
    }
}

// ---------------- K5: recompute h1, BN1+GELU, write AbfT[b][p][c] bf16 (conv2 B^T operand)
__global__ __launch_bounds__(256) void k_gelutr(char* __restrict__ ws,
    const float* __restrict__ g1, const float* __restrict__ be1, const float* __restrict__ bd1)
{
    const float* TT   = (const float*)(ws + WS_TT);
    const float* W2   = (const float*)(ws + WS_W2);
    const float* cvec = (const float*)(ws + WS_C);
    const float* rs1  = (const float*)(ws + WS_RS1);
    const float* st1  = (const float*)(ws + WS_ST1);
    unsigned short* A = (unsigned short*)(ws + WS_ABT);
    __shared__ float Ts[32][8];
    __shared__ float cmean[32], crg[32], cbe[32], crs[32], cbd[32];
    int bid = blockIdx.x, tid = threadIdx.x;
    int b = bid >> 4, cg = bid & 15, c0 = cg*32;
    {
        int cl = tid >> 3, h = tid & 7;
        Ts[cl][h] = TT[(size_t)(c0+cl)*512 + b*8 + h];
    }
    if (tid < 32) {
        int c = c0 + tid;
        float mean = st1[c] * (1.0f/16384.0f);
        float var  = st1[512+c] * (1.0f/16384.0f) - mean*mean;
        cmean[tid] = mean;
        crg[tid]   = rsqrtf(var + 1e-5f) * g1[c];
        cbe[tid]   = be1[c];
        crs[tid]   = rs1[c];
        cbd[tid]   = bd1[c];
    }
    __syncthreads();
    int p = tid;
    f32x4 wa = *(const f32x4*)(W2 + p*8);
    f32x4 wb = *(const f32x4*)(W2 + p*8 + 4);
    float cp = cvec[p];
    unsigned opack[16];
    #pragma unroll
    for (int cl = 0; cl < 32; ++cl) {
        float hv = fmaf(cp, crs[cl], cbd[cl]);
        hv = fmaf(wa[0], Ts[cl][0], hv); hv = fmaf(wa[1], Ts[cl][1], hv);
        hv = fmaf(wa[2], Ts[cl][2], hv); hv = fmaf(wa[3], Ts[cl][3], hv);
        hv = fmaf(wb[0], Ts[cl][4], hv); hv = fmaf(wb[1], Ts[cl][5], hv);
        hv = fmaf(wb[2], Ts[cl][6], hv); hv = fmaf(wb[3], Ts[cl][7], hv);
        float xn = fmaf(hv - cmean[cl], crg[cl], cbe[cl]);
        float gel = 0.5f * xn * (1.0f + erff(xn * 0.7071067811865475f));
        unsigned bs = (unsigned)f2bf(gel);
        if (cl & 1) opack[cl >> 1] |= bs << 16; else opack[cl >> 1] = bs;
    }
    u32x4* dst = (u32x4*)(A + (size_t)(b*256 + p)*512 + c0);
    #pragma unroll
    for (int i = 0; i < 4; ++i) dst[i] = *(((u32x4*)opack) + i);
}

// ---------------- K7: BN2 stats over h2 (= d_out)
__global__ __launch_bounds__(256) void k_stats2(const float* __restrict__ h2, char* __restrict__ ws)
{
    float* st2 = (float*)(ws + WS_ST2);
    __shared__ float reds[4], redq[4];
    int oc = blockIdx.x, tid = threadIdx.x;
    float s = 0.f, q2 = 0.f;
    for (int b = 0; b < 64; ++b) {
        float v = h2[((size_t)b*1024 + oc)*256 + tid];
        s += v; q2 = fmaf(v, v, q2);
    }
    for (int off = 32; off; off >>= 1) { s += __shfl_down(s, off); q2 += __shfl_down(q2, off); }
    int lane = tid & 63, w = tid >> 6;
    if (lane == 0) { reds[w] = s; redq[w] = q2; }
    __syncthreads();
    if (tid == 0) {
        st2[oc]      = reds[0]+reds[1]+reds[2]+reds[3];
        st2[1024+oc] = redq[0]+redq[1]+redq[2]+redq[3];
    }
}

// ---------------- K8: BN2 + GELU in place on d_out
__global__ __launch_bounds__(256) void k_final(float* __restrict__ out, const char* __restrict__ ws,
    const float* __restrict__ g2, const float* __restrict__ be2)
{
    const float* st2 = (const float*)(ws + WS_ST2);
    int idx = (blockIdx.x*256 + threadIdx.x)*4;
    int oc = (idx >> 8) & 1023;
    float mean = st2[oc] * (1.0f/16384.0f);
    float var  = st2[1024+oc] * (1.0f/16384.0f) - mean*mean;
    float rstd = rsqrtf(var + 1e-5f);
    float g = g2[oc], be = be2[oc];
    f32x4 v = *(f32x4*)(out + idx);
    #pragma unroll
    for (int t = 0; t < 4; ++t) {
        float xn = (v[t] - mean) * rstd * g + be;
        v[t] = 0.5f * xn * (1.0f + erff(xn * 0.7071067811865475f));
    }
    *(f32x4*)(out + idx) = v;
}

extern "C" void kernel_launch(void* const* d_in, const int* in_sizes, int n_in,
                              void* d_out, int out_size, void* d_ws, size_t ws_size,
                              hipStream_t stream)
{
    const float* x1  = (const float*)d_in[0];
    const float* x2  = (const float*)d_in[1];
    const float* x3  = (const float*)d_in[2];
    const float* wq  = (const float*)d_in[3];
    const float* bq  = (const float*)d_in[4];
    const float* wk  = (const float*)d_in[5];
    const float* bk  = (const float*)d_in[6];
    const float* wv  = (const float*)d_in[7];
    const float* bv  = (const float*)d_in[8];
    const float* wfc = (const float*)d_in[9];
    const float* bfc = (const float*)d_in[10];
    const float* wc1 = (const float*)d_in[11];
    const float* bc1 = (const float*)d_in[12];
    const float* wc2 = (const float*)d_in[13];
    const float* bc2 = (const float*)d_in[14];
    const float* wc3 = (const float*)d_in[15];
    const float* bc3 = (const float*)d_in[16];
    const float* wd1 = (const float*)d_in[17];
    const float* bd1 = (const float*)d_in[18];
    const float* g1  = (const float*)d_in[19];
    const float* be1 = (const float*)d_in[20];
    const float* wd2 = (const float*)d_in[21];
    const float* bd2 = (const float*)d_in[22];
    const float* g2  = (const float*)d_in[23];
    const float* be2 = (const float*)d_in[24];
    char* ws = (char*)d_ws;
    float* out = (float*)d_out;
    if (ws_size < (size_t)WS_END) return;  // need ~22.3 MB scratch

    k_prep<<<2057, 256, 0, stream>>>(wq,bq,wk,bk,wv,bv,wfc,bfc,wd1,wd2,ws);
    k_tvec<<<1536, 256, 0, stream>>>(x1,x2,x3,wc1,bc1,wc2,bc2,wc3,bc3,ws);
    k_attn<<<768, 256, 0, stream>>>(ws);
    // conv1 collapsed: T[oc][b*8+h] = wd1 x S3^T   (M=512, N=512, K=1536)
    k_gemm_nt<<<dim3(4,4,1), 256, 0, stream>>>(
        (const unsigned short*)(ws+WS_WD1B), (const unsigned short*)(ws+WS_S3),
        (float*)(ws+WS_TT), nullptr, 1536, 1536, 512, 1536, 0L, 0L);
    k_stats1<<<512, 256, 0, stream>>>(ws, bd1);
    k_gelutr<<<1024, 256, 0, stream>>>(ws, g1, be1, bd1);
    // conv2: h2[b][oc2][p] = wd2 x gelu1[b]^T + bd2  (M=1024, N=256, K=512, batch=64) -> d_out
    k_gemm_nt<<<dim3(8,2,64), 256, 0, stream>>>(
        (const unsigned short*)(ws+WS_WD2B), (const unsigned short*)(ws+WS_ABT),
        out, bd2, 512, 512, 256, 512, (long)256*512, (long)1024*256);
    k_stats2<<<1024, 256, 0, stream>>>(out, ws);
    k_final<<<16384, 256, 0, stream>>>(out, ws, g2, be2);
}